// Round 7
// baseline (187.118 us; speedup 1.0000x reference)
//
#include <hip/hip_runtime.h>
#include <hip/hip_bf16.h>
#include <math.h>

#define ICH   3
#define OCH   16
#define ID    18
#define IH    34
#define IW    34
#define OD    16
#define OH    32
#define OW    32
#define NB    128
#define PLANE_W  36                 // padded row stride (aligned float4 at w%4==0)
#define PLANE_SZ (PLANE_W * IH)     // 36*34 = 1224 floats per plane
#define DCHUNK   2
#define IN_D     (DCHUNK + 2)       // 4 input d-planes per chunk
#define SPATIAL  (OD * OH * OW)     // 16384 per (b,c)
#define EPSV     1e-5f

__device__ __forceinline__ unsigned short f2bf(float f) {
    unsigned int u = __float_as_uint(f);
    unsigned int r = (u + 0x7fffu + ((u >> 16) & 1u)) >> 16;
    return (unsigned short)r;
}

// ===== conv: R1 structure (proven ~107 us; every structural deviation since
// regressed). 1024 blocks, 59.4 KB LDS, fp32 staging, in-thread dz reuse,
// all-16-oc unroll w/ compile-time weight idx (s_load path), VGPR ~88 no spill.
// Do NOT: raise min-waves (forces spill), fp16/bf16 staging (cvt VALU +
// scratch), split dz across waves (2x staging per output).
// CHANGED vs R6: y stored POSITION-MAJOR y[b][d][h][w][c] (16ch x 2B = 32B
// per position) -> per-thread 128B contiguous store, wave 8KB sequential.
// Kills the 32KB power-of-2 stride pattern on both sides of the y round-trip.
__global__ __launch_bounds__(256, 2) void conv_stats_kernel(
    const float* __restrict__ x, const float* __restrict__ cw,
    const float* __restrict__ cb, const float* __restrict__ mult,
    unsigned short* __restrict__ y, float* __restrict__ stats)
{
    __shared__ float sx[ICH][IN_D][PLANE_SZ];
    __shared__ float wsum[4][OCH], wsq[4][OCH];

    const int blk = blockIdx.x;
    const int b = blk >> 3;
    const int d0 = (blk & 7) * DCHUNK;
    const int tid = threadIdx.x;

    for (int idx = tid; idx < ICH * IN_D * IH * IW; idx += 256) {
        int t = idx;
        const int wcol = t % IW; t /= IW;
        const int hrow = t % IH; t /= IH;
        const int dz = t % IN_D; t /= IN_D;
        const int ic = t;
        sx[ic][dz][hrow * PLANE_W + wcol] =
            x[(((size_t)(b * ICH + ic) * ID) + (d0 + dz)) * (IH * IW) + hrow * IW + wcol];
    }
    __syncthreads();

    const int h  = tid >> 3;        // 0..31
    const int wq = (tid & 7) << 2;  // 0,4,...,28

    float ssum[OCH], ssq[OCH];
#pragma unroll
    for (int c = 0; c < OCH; c++) { ssum[c] = 0.0f; ssq[c] = 0.0f; }

    for (int dz = 0; dz < DCHUNK; dz++) {
        float acc[OCH][4];
#pragma unroll
        for (int c = 0; c < OCH; c++) {
            const float bv = cb[c];
            acc[c][0] = bv; acc[c][1] = bv; acc[c][2] = bv; acc[c][3] = bv;
        }

        for (int ic = 0; ic < ICH; ic++) {
            for (int kd = 0; kd < 3; kd++) {
#pragma unroll
                for (int kh = 0; kh < 3; kh++) {
                    const float* row = &sx[ic][dz + kd][(h + kh) * PLANE_W + wq];
                    const float4 v0 = *(const float4*)row;
                    const float2 v1 = *(const float2*)(row + 4);
                    float in[6];
                    in[0] = v0.x; in[1] = v0.y; in[2] = v0.z; in[3] = v0.w;
                    in[4] = v1.x; in[5] = v1.y;
                    const float* wrow = &cw[(size_t)(ic * 3 + kd) * 9 + kh * 3];
#pragma unroll
                    for (int kw = 0; kw < 3; kw++) {
#pragma unroll
                        for (int c = 0; c < OCH; c++) {
                            const float wv = wrow[(size_t)c * (ICH * 27) + kw];
                            acc[c][0] = fmaf(in[kw + 0], wv, acc[c][0]);
                            acc[c][1] = fmaf(in[kw + 1], wv, acc[c][1]);
                            acc[c][2] = fmaf(in[kw + 2], wv, acc[c][2]);
                            acc[c][3] = fmaf(in[kw + 3], wv, acc[c][3]);
                        }
                    }
                }
            }
        }

        const int d = d0 + dz;
        // fold multiplier in place + stats
#pragma unroll
        for (int c = 0; c < OCH; c++) {
            const float m = mult[c];
            acc[c][0] *= m; acc[c][1] *= m; acc[c][2] *= m; acc[c][3] *= m;
            ssum[c] += (acc[c][0] + acc[c][1]) + (acc[c][2] + acc[c][3]);
            ssq[c]  += (acc[c][0] * acc[c][0] + acc[c][1] * acc[c][1])
                     + (acc[c][2] * acc[c][2] + acc[c][3] * acc[c][3]);
        }
        // transposed store: 4 positions x (16ch x bf16 = 32B), 128B contiguous
        const size_t pos0 = (((size_t)b * OD + d) * OH + h) * OW + wq;
#pragma unroll
        for (int j = 0; j < 4; j++) {
            unsigned int u[8];
#pragma unroll
            for (int k = 0; k < 8; k++) {
                u[k] = (unsigned int)f2bf(acc[2 * k][j])
                     | ((unsigned int)f2bf(acc[2 * k + 1][j]) << 16);
            }
            unsigned short* dst = y + (pos0 + j) * OCH;
            uint4 q0; q0.x = u[0]; q0.y = u[1]; q0.z = u[2]; q0.w = u[3];
            uint4 q1; q1.x = u[4]; q1.y = u[5]; q1.z = u[6]; q1.w = u[7];
            *(uint4*)dst = q0;
            *(uint4*)(dst + 8) = q1;
        }
    }

#pragma unroll
    for (int c = 0; c < OCH; c++) {
        for (int off = 32; off > 0; off >>= 1) {
            ssum[c] += __shfl_down(ssum[c], off);
            ssq[c]  += __shfl_down(ssq[c], off);
        }
    }
    const int wave = tid >> 6, lane = tid & 63;
    if (lane == 0) {
#pragma unroll
        for (int c = 0; c < OCH; c++) { wsum[wave][c] = ssum[c]; wsq[wave][c] = ssq[c]; }
    }
    __syncthreads();
    if (tid < OCH) {
        float s = 0.0f, q = 0.0f;
#pragma unroll
        for (int k = 0; k < 4; k++) { s += wsum[k][tid]; q += wsq[k][tid]; }
        atomicAdd(&stats[(b * OCH + tid) * 2 + 0], s);
        atomicAdd(&stats[(b * OCH + tid) * 2 + 1], q);
    }
}

// ===== norm_max v4: pure streaming over position-major y. Each thread reads
// 8 positions x 32B = 256B contiguous (16x uint4, two batches of 8), a wave
// streams 16KB sequential. No strided gather anywhere. 1024 blocks.
__global__ __launch_bounds__(256) void norm_max_kernel(
    const unsigned short* __restrict__ y, const float* __restrict__ stats,
    const float* __restrict__ mult, float* __restrict__ out)
{
    const int blk = blockIdx.x;
    const int b   = blk >> 3;
    const int seg = blk & 7;
    const int tid = threadIdx.x;

    __shared__ float srs_s[OCH], snb_s[OCH], smul_s[OCH];
    if (tid < OCH) {
        const float s  = stats[(b * OCH + tid) * 2 + 0];
        const float sq = stats[(b * OCH + tid) * 2 + 1];
        const float mean = s * (1.0f / (float)SPATIAL);
        float var = sq * (1.0f / (float)SPATIAL) - mean * mean;
        var = fmaxf(var, 0.0f);
        const float rs = rsqrtf(var + EPSV);
        srs_s[tid]  = rs;
        snb_s[tid]  = -mean * rs;      // normalized = v*rs + nb
        smul_s[tid] = mult[tid];
    }
    __syncthreads();

    float rs[OCH], nb[OCH], mm[OCH];
#pragma unroll
    for (int c = 0; c < OCH; c++) { rs[c] = srs_s[c]; nb[c] = snb_s[c]; mm[c] = smul_s[c]; }

    const size_t p0 = (size_t)b * SPATIAL + seg * 2048 + tid * 8;  // position index
    const uint4* src = (const uint4*)(y + p0 * OCH);               // 2 uint4 / position

    float res[8];
#pragma unroll
    for (int half = 0; half < 2; half++) {
        uint4 v[8];
#pragma unroll
        for (int i = 0; i < 8; i++) v[i] = src[half * 8 + i];
#pragma unroll
        for (int j = 0; j < 4; j++) {
            const unsigned int uu[8] = {
                v[2 * j].x, v[2 * j].y, v[2 * j].z, v[2 * j].w,
                v[2 * j + 1].x, v[2 * j + 1].y, v[2 * j + 1].z, v[2 * j + 1].w };
            float best = -INFINITY;
#pragma unroll
            for (int k = 0; k < 8; k++) {
                float f0 = __uint_as_float(uu[k] << 16)         * rs[2 * k]     + nb[2 * k];
                float f1 = __uint_as_float(uu[k] & 0xffff0000u) * rs[2 * k + 1] + nb[2 * k + 1];
                f0 = fminf(fmaxf(f0, -1.0f), 1.0f) * mm[2 * k];
                f1 = fminf(fmaxf(f1, -1.0f), 1.0f) * mm[2 * k + 1];
                best = fmaxf(best, fmaxf(f0, f1));
            }
            res[half * 4 + j] = best;
        }
    }

    float* op = out + p0;
    float4 o0; o0.x = res[0]; o0.y = res[1]; o0.z = res[2]; o0.w = res[3];
    float4 o1; o1.x = res[4]; o1.y = res[5]; o1.z = res[6]; o1.w = res[7];
    *(float4*)op = o0;
    *(float4*)(op + 4) = o1;
}

extern "C" void kernel_launch(void* const* d_in, const int* in_sizes, int n_in,
                              void* d_out, int out_size, void* d_ws, size_t ws_size,
                              hipStream_t stream) {
    const float* x    = (const float*)d_in[0];
    const float* cw   = (const float*)d_in[1];
    const float* cb   = (const float*)d_in[2];
    const float* mult = (const float*)d_in[3];
    float* out = (float*)d_out;

    unsigned short* y = (unsigned short*)d_ws;   // position-major, 64 MB
    float* stats = (float*)((char*)d_ws + (size_t)NB * OCH * SPATIAL * sizeof(unsigned short));

    hipMemsetAsync(stats, 0, (size_t)NB * OCH * 2 * sizeof(float), stream);
    conv_stats_kernel<<<NB * 8, 256, 0, stream>>>(x, cw, cb, mult, y, stats);
    norm_max_kernel<<<NB * 8, 256, 0, stream>>>(y, stats, mult, out);
}